// Round 2
// baseline (416.742 us; speedup 1.0000x reference)
//
#include <hip/hip_runtime.h>

typedef __bf16 bf16;
typedef __attribute__((ext_vector_type(8))) __bf16 bf16x8;
typedef __attribute__((ext_vector_type(4))) __bf16 bf16x4;
typedef __attribute__((ext_vector_type(4))) short short4_t;
typedef __attribute__((ext_vector_type(4))) float floatx4;

typedef const void __attribute__((address_space(1)))* gas1p;
typedef void __attribute__((address_space(3)))* las3p;

#define LOG2E 1.44269504088896340736f

static constexpr int D_MODEL = 1024;
static constexpr int N_HEADS = 16;
static constexpr int HDIM    = 64;
static constexpr int BSZ     = 8;
static constexpr int SEQ     = 1024;
static constexpr int ROWS    = BSZ * SEQ;   // 8192
static constexpr int FF_IN   = 1088;        // 17*64
static constexpr int FF_HID  = 2048;
static constexpr int QKV_LD  = 3072;        // q|k|v row stride in qkv buffer

__device__ __forceinline__ floatx4 mfma_bf16(bf16x8 a, bf16x8 b, floatx4 c) {
  return __builtin_amdgcn_mfma_f32_16x16x32_bf16(a, b, c, 0, 0, 0);
}

__device__ __forceinline__ floatx4 mfma16(bf16x4 a, bf16x4 b, floatx4 c) {
#if __has_builtin(__builtin_amdgcn_mfma_f32_16x16x16_bf16)
  return __builtin_amdgcn_mfma_f32_16x16x16_bf16(a, b, c, 0, 0, 0);
#else
  return __builtin_amdgcn_mfma_f32_16x16x16bf16_1k(
      __builtin_bit_cast(short4_t, a), __builtin_bit_cast(short4_t, b), c, 0, 0, 0);
#endif
}

__device__ __forceinline__ float flex_load(const void* src, size_t idx, int isbf) {
  return isbf ? (float)((const bf16*)src)[idx] : ((const float*)src)[idx];
}

// ---------------- dtype detection (fp32 vs bf16 storage) ----------------
__global__ void detect_kernel(const unsigned* __restrict__ w, int* __restrict__ flag) {
  __shared__ int cnt;
  if (threadIdx.x == 0) cnt = 0;
  __syncthreads();
  int hits = 0;
  for (int i = threadIdx.x; i < 4096; i += 256) {
    const unsigned v = w[(size_t)i * 997 + 13];
    const unsigned b = (v >> 8) & 0x7F;
    hits += (b >= 0x3B && b <= 0x41) ? 1 : 0;
  }
  atomicAdd(&cnt, hits);
  __syncthreads();
  if (threadIdx.x == 0) *flag = (cnt > 2048) ? 1 : 0;
}

// ---------------- x -> bf16, 8 elems/thread ----------------
__global__ __launch_bounds__(256)
void x_to_bf16_kernel(const void* __restrict__ src, bf16* __restrict__ dst,
                      const int* __restrict__ flag) {
  const int isbf = *flag;
  const size_t i = ((size_t)blockIdx.x * 256 + threadIdx.x) * 8;
  bf16x8 o;
  if (isbf) {
    o = *reinterpret_cast<const bf16x8*>((const bf16*)src + i);
  } else {
    const float4 f0 = *reinterpret_cast<const float4*>((const float*)src + i);
    const float4 f1 = *reinterpret_cast<const float4*>((const float*)src + i + 4);
    o[0] = (bf16)f0.x; o[1] = (bf16)f0.y; o[2] = (bf16)f0.z; o[3] = (bf16)f0.w;
    o[4] = (bf16)f1.x; o[5] = (bf16)f1.y; o[6] = (bf16)f1.z; o[7] = (bf16)f1.w;
  }
  *reinterpret_cast<bf16x8*>(dst + i) = o;
}

// ---------------- all 6 biases -> one fp32 buffer (q scaled 1/8 * log2e) ----------------
__global__ __launch_bounds__(256)
void bias_all_kernel(const void* bq, const void* bk, const void* bv,
                     const void* bin, const void* b1, const void* b2,
                     float* __restrict__ dst, const int* __restrict__ flag) {
  const int isbf = *flag;
  const int i = blockIdx.x * 256 + threadIdx.x;
  if (i < 1024)      dst[i] = flex_load(bq, i, isbf) * (0.125f * LOG2E);
  else if (i < 2048) dst[i] = flex_load(bk, i - 1024, isbf);
  else if (i < 3072) dst[i] = flex_load(bv, i - 2048, isbf);
  else if (i < 3136) dst[i] = flex_load(bin, i - 3072, isbf);
  else if (i < 5184) dst[i] = flex_load(b1, i - 3136, isbf);
  else if (i < 6208) dst[i] = flex_load(b2, i - 5184, isbf);
}

// ---------------- all weight transposes in one launch ----------------
struct TransJobs {
  const void* src[6];
  bf16* dst[6];
  int R[6], C[6];
  int tiles_x[6];
  int tile_base[7];
  float scale[6];
};

__global__ __launch_bounds__(256)
void transpose_all_kernel(TransJobs J, const int* __restrict__ flag) {
  __shared__ float tile[32][33];
  const int isbf = *flag;
  const int bid = blockIdx.x;
  int j = 0;
#pragma unroll
  for (int t = 1; t < 6; t++) j += (bid >= J.tile_base[t]) ? 1 : 0;
  const int t = bid - J.tile_base[j];
  const int c0 = (t % J.tiles_x[j]) * 32, r0 = (t / J.tiles_x[j]) * 32;
  const void* src = J.src[j];
  bf16* dst = J.dst[j];
  const int R = J.R[j], C = J.C[j];
  const float scale = J.scale[j];
  const int tx = threadIdx.x & 31, ty = threadIdx.x >> 5;
  for (int i = ty; i < 32; i += 8)
    tile[i][tx] = flex_load(src, (size_t)(r0 + i) * C + (c0 + tx), isbf);
  __syncthreads();
  for (int i = ty; i < 32; i += 8)
    dst[(size_t)(c0 + i) * R + (r0 + tx)] = (bf16)(tile[tx][i] * scale);
}

// v rows of qkv buffer [b, i, 2048 + h*64 + d] (stride QKV_LD) -> vt [b, h, d, i]
__global__ __launch_bounds__(256)
void transpose_v_kernel(const bf16* __restrict__ v, bf16* __restrict__ vt) {
  __shared__ float tile[32][33];
  const int bh = blockIdx.z, b = bh >> 4, h = bh & 15;
  const int s0 = blockIdx.x * 32, d0 = blockIdx.y * 32;
  const int tx = threadIdx.x & 31, ty = threadIdx.x >> 5;
  const bf16* src = v + (size_t)b * SEQ * QKV_LD + 2048 + h * HDIM;
  bf16* dst = vt + (size_t)bh * HDIM * SEQ;
  for (int i = ty; i < 32; i += 8)
    tile[i][tx] = (float)src[(size_t)(s0 + i) * QKV_LD + d0 + tx];
  __syncthreads();
  for (int i = ty; i < 32; i += 8)
    dst[(size_t)(d0 + i) * SEQ + s0 + tx] = (bf16)tile[tx][i];
}

// ---------------- GEMM: C[M,N] = A[M,K] @ BT[N,K]^T + bias ----------------
// Round-2 rewrite: BM=256, BN=128, BK=64, 512 threads (8 waves, per-wave 64x64
// geometry identical to the previously verified 4-wave version), 3-stage LDS
// rotation (144 KB, 1 block/CU) with raw s_barrier + COUNTED s_waitcnt vmcnt
// (T3/T4): in steady state vmcnt(12) leaves tiles kt+2,kt+3 (6 loads each) in
// flight across the barrier and proves tile kt+1 landed. Never drains to 0 in
// the main loop -> removes the m97-structure barrier-drain stall. Tile kt+1's
// loads get ~2 full compute iterations of slack (covers HBM-miss latency).
// XOR staging swizzle unchanged (gcol = col ^ (row&7) on the global side).
template <int BN, bool DO_RELU, bool OUT_FLEX>
__global__ __launch_bounds__(512, 2)
void gemm_bt(const bf16* __restrict__ A, const bf16* __restrict__ BT,
             const float* __restrict__ bias,
             void* __restrict__ Cv, int N, int K, int ldc,
             bf16* __restrict__ C2, int ldc2, int nsplit, int nvalid,
             const int* __restrict__ flag) {
  constexpr int BM = 256, BK = 64;
  constexpr int TCN = BN / 32;                 // 4
  static_assert(BN == 128, "BN must be 128");
  __shared__ bf16 As[3][BM * BK];              // 3 x 32 KB
  __shared__ bf16 Bs[3][BN * BK];              // 3 x 16 KB
  const int tid = threadIdx.x;
  const int wave = tid >> 6, lane = tid & 63;
  const int quad = lane >> 4, lo = lane & 15;
  const int wm = wave >> 1, wn = wave & 1;     // 4 M-waves x 2 N-waves
  const int m0 = blockIdx.x * BM;
  const int n0 = blockIdx.y * BN;
  const int NT = K / BK;

  floatx4 acc[4][TCN];
#pragma unroll
  for (int i = 0; i < 4; i++)
#pragma unroll
    for (int j = 0; j < TCN; j++) acc[i][j] = floatx4{0.f, 0.f, 0.f, 0.f};

  auto stage = [&](int t, int cb) {
    const size_t kb = (size_t)t * BK;
#pragma unroll
    for (int u = 0; u < 4; u++) {               // A: 256x64 = 4 loads/thread
      const int c = u * 512 + tid;
      const int row = c >> 3;
      const int gcol = (c & 7) ^ (row & 7);
      __builtin_amdgcn_global_load_lds(
          (gas1p)(A + (size_t)(m0 + row) * K + kb + gcol * 8),
          (las3p)(&As[cb][c * 8]), 16, 0, 0);
    }
#pragma unroll
    for (int u = 0; u < 2; u++) {               // B: 128x64 = 2 loads/thread
      const int c = u * 512 + tid;
      const int row = c >> 3;
      const int gcol = (c & 7) ^ (row & 7);
      __builtin_amdgcn_global_load_lds(
          (gas1p)(BT + (size_t)(n0 + row) * K + kb + gcol * 8),
          (las3p)(&Bs[cb][c * 8]), 16, 0, 0);
    }
  };

  // prologue: 3 tiles in flight; drain only tile 0 (12 = tiles 1,2 in flight)
  stage(0, 0); stage(1, 1); stage(2, 2);
  asm volatile("s_waitcnt vmcnt(12)" ::: "memory");
  asm volatile("s_barrier" ::: "memory");

  for (int kt = 0; kt < NT; ++kt) {
    const int cb = kt % 3;
    const bf16* Asc = As[cb];
    const bf16* Bsc = Bs[cb];
#pragma unroll
    for (int kk = 0; kk < 2; kk++) {
      bf16x8 af[4], bfr[TCN];
#pragma unroll
      for (int tr = 0; tr < 4; tr++) {
        const int row = wm * 64 + tr * 16 + lo;
        const int cc = (kk * 4 + quad) ^ (lo & 7);
        af[tr] = *reinterpret_cast<const bf16x8*>(Asc + row * BK + cc * 8);
      }
#pragma unroll
      for (int tc = 0; tc < TCN; tc++) {
        const int row = wn * (BN / 2) + tc * 16 + lo;
        const int cc = (kk * 4 + quad) ^ (lo & 7);
        bfr[tc] = *reinterpret_cast<const bf16x8*>(Bsc + row * BK + cc * 8);
      }
#pragma unroll
      for (int tr = 0; tr < 4; tr++)
#pragma unroll
        for (int tc = 0; tc < TCN; tc++)
          acc[tr][tc] = mfma_bf16(af[tr], bfr[tc], acc[tr][tc]);
    }
    if (kt + 1 < NT) {
      // all my ds_reads of buf cb consumed (compiler drains lgkm before last
      // MFMA); explicit drain is belt-and-braces, then protect buf reuse.
      asm volatile("s_waitcnt lgkmcnt(0)" ::: "memory");
      asm volatile("s_barrier" ::: "memory");
      if (kt + 3 < NT) stage(kt + 3, cb);       // (kt+3)%3 == cb
      // need tile kt+1 resident; allow 6*ahead newer loads to stay in flight
      const int ahead = ((kt + 3 < NT) ? (kt + 3) : (NT - 1)) - (kt + 1);
      if (ahead >= 2)      asm volatile("s_waitcnt vmcnt(12)" ::: "memory");
      else if (ahead == 1) asm volatile("s_waitcnt vmcnt(6)" ::: "memory");
      else                 asm volatile("s_waitcnt vmcnt(0)" ::: "memory");
      asm volatile("s_barrier" ::: "memory");
    }
  }

  const int isbf = OUT_FLEX ? *flag : 1;
#pragma unroll
  for (int tc = 0; tc < TCN; tc++) {
    const int col = n0 + wn * (BN / 2) + tc * 16 + lo;
    const float bval = bias[col];
    if (col < nsplit) {
#pragma unroll
      for (int tr = 0; tr < 4; tr++) {
        const int rbase = m0 + wm * 64 + tr * 16 + quad * 4;
#pragma unroll
        for (int r = 0; r < 4; r++) {
          float v = acc[tr][tc][r] + bval;
          if (DO_RELU) v = fmaxf(v, 0.f);
          const size_t idx = (size_t)(rbase + r) * ldc + col;
          if (!OUT_FLEX || isbf) ((bf16*)Cv)[idx] = (bf16)v;
          else                   ((float*)Cv)[idx] = v;
        }
      }
    } else if (col < nvalid) {
#pragma unroll
      for (int tr = 0; tr < 4; tr++) {
        const int rbase = m0 + wm * 64 + tr * 16 + quad * 4;
#pragma unroll
        for (int r = 0; r < 4; r++) {
          float v = acc[tr][tc][r] + bval;
          if (DO_RELU) v = fmaxf(v, 0.f);
          C2[(size_t)(rbase + r) * ldc2 + (col - nsplit)] = (bf16)v;
        }
      }
    }
  }
}

// ---------------- flash attention: S^T formulation + LDS staging ----------------
// Reverted to the 16 KB single-buffer structure (round-1 dbuf cost occupancy
// 24% -> 18.6% and was net-neutral/negative). Keeps the LOG2E-in-q-scale fold
// (exp2f directly) and setprio around MFMA clusters.
__global__ __launch_bounds__(256)
void attn_kernel(const bf16* __restrict__ QKV, const bf16* __restrict__ Vt,
                 bf16* __restrict__ Cc) {
  __shared__ bf16 Ks[64 * 64];
  __shared__ bf16 Vs[64 * 64];
  const int bid = blockIdx.x;
  const int xcd = bid & 7, g = bid >> 3;
  const int ib = g & 7, bh = (g >> 3) * 8 + xcd;
  const int b = bh >> 4, h = bh & 15;
  const int i0 = ib * 128;
  const int tid = threadIdx.x, wave = tid >> 6, lane = tid & 63;
  const int quad = lane >> 4, lo = lane & 15;
  const int iw = i0 + wave * 32;
  const bf16* qptr = QKV + (size_t)b * SEQ * QKV_LD + h * HDIM;
  const bf16* kptr = QKV + (size_t)b * SEQ * QKV_LD + 1024 + h * HDIM;
  const bf16* vptr = Vt + (size_t)bh * HDIM * SEQ;

  bf16x8 qf[2][2];
#pragma unroll
  for (int it = 0; it < 2; it++)
#pragma unroll
    for (int kf = 0; kf < 2; kf++)
      qf[it][kf] = *reinterpret_cast<const bf16x8*>(
          qptr + (size_t)(iw + it * 16 + lo) * QKV_LD + kf * 32 + quad * 8);

  floatx4 oacc[2][4];
  float lrow[2] = {0.f, 0.f};
#pragma unroll
  for (int it = 0; it < 2; it++)
#pragma unroll
    for (int dt = 0; dt < 4; dt++) oacc[it][dt] = floatx4{0.f, 0.f, 0.f, 0.f};

  for (int jb = 0; jb < SEQ / 64; jb++) {
    const int j0 = jb * 64;
#pragma unroll
    for (int u = 0; u < 2; u++) {
      const int c = u * 256 + tid;
      const int row = c >> 3, col = c & 7;
      const int gcol = col ^ (row & 7);
      __builtin_amdgcn_global_load_lds(
          (gas1p)(kptr + (size_t)(j0 + row) * QKV_LD + gcol * 8),
          (las3p)(Ks + c * 8), 16, 0, 0);
      __builtin_amdgcn_global_load_lds(
          (gas1p)(vptr + (size_t)row * SEQ + j0 + gcol * 8),
          (las3p)(Vs + c * 8), 16, 0, 0);
    }
    __syncthreads();

    floatx4 sacc[2][4];
#pragma unroll
    for (int it = 0; it < 2; it++)
#pragma unroll
      for (int mt = 0; mt < 4; mt++) sacc[it][mt] = floatx4{0.f, 0.f, 0.f, 0.f};
    __builtin_amdgcn_s_setprio(1);
#pragma unroll
    for (int mt = 0; mt < 4; mt++) {
      const int r = mt * 16 + lo;
      const int cc0 = quad ^ (lo & 7);
      const int cc1 = (4 + quad) ^ (lo & 7);
      const bf16x8 k0 = *reinterpret_cast<const bf16x8*>(Ks + r * 64 + cc0 * 8);
      const bf16x8 k1 = *reinterpret_cast<const bf16x8*>(Ks + r * 64 + cc1 * 8);
#pragma unroll
      for (int it = 0; it < 2; it++) {
        sacc[it][mt] = mfma_bf16(k0, qf[it][0], sacc[it][mt]);
        sacc[it][mt] = mfma_bf16(k1, qf[it][1], sacc[it][mt]);
      }
    }
    __builtin_amdgcn_s_setprio(0);

    if (j0 == (iw & ~63)) {
#pragma unroll
      for (int it = 0; it < 2; it++) {
        const int ig = iw + it * 16 + lo;
#pragma unroll
        for (int mt = 0; mt < 4; mt++)
#pragma unroll
          for (int r = 0; r < 4; r++)
            if (j0 + mt * 16 + quad * 4 + r == ig) sacc[it][mt][r] = -1e30f;
      }
    }

    bf16x4 pfrag[2][4];
#pragma unroll
    for (int it = 0; it < 2; it++) {
      float s0 = 0.f, s1 = 0.f;
#pragma unroll
      for (int mt = 0; mt < 4; mt++) {
        bf16x4 pk;
#pragma unroll
        for (int r = 0; r < 4; r++) {
          const float p = exp2f(sacc[it][mt][r]);  // LOG2E folded into q scale
          if (mt & 1) s1 += p; else s0 += p;
          pk[r] = (bf16)p;
        }
        pfrag[it][mt] = pk;
      }
      float s = s0 + s1;
      s += __shfl_xor(s, 16);
      s += __shfl_xor(s, 32);
      lrow[it] += s;
    }

    __builtin_amdgcn_s_setprio(1);
#pragma unroll
    for (int dt = 0; dt < 4; dt++) {
      const int r = dt * 16 + lo;
#pragma unroll
      for (int kt = 0; kt < 4; kt++) {
        const int gch = kt * 2 + (quad >> 1);
        const int cc = gch ^ (lo & 7);
        const bf16x4 vf = *reinterpret_cast<const bf16x4*>(
            Vs + r * 64 + cc * 8 + (quad & 1) * 4);
#pragma unroll
        for (int it = 0; it < 2; it++)
          oacc[it][dt] = mfma16(vf, pfrag[it][kt], oacc[it][dt]);
      }
    }
    __builtin_amdgcn_s_setprio(0);
    __syncthreads();
  }

#pragma unroll
  for (int it = 0; it < 2; it++) {
    const int ig = iw + it * 16 + lo;
    const float inv = 1.0f / lrow[it];
    bf16* cb = Cc + ((size_t)b * SEQ + ig) * FF_IN + h * HDIM;
#pragma unroll
    for (int dt = 0; dt < 4; dt++) {
      bf16x4 o;
#pragma unroll
      for (int r = 0; r < 4; r++) o[r] = (bf16)(oacc[it][dt][r] * inv);
      *reinterpret_cast<bf16x4*>(cb + dt * 16 + quad * 4) = o;
    }
  }
}

// ---------------- launch ----------------
extern "C" void kernel_launch(void* const* d_in, const int* in_sizes, int n_in,
                              void* d_out, int out_size, void* d_ws, size_t ws_size,
                              hipStream_t stream) {
  (void)in_sizes; (void)n_in; (void)out_size; (void)ws_size;
  const void* x   = d_in[0];
  const void* Wq  = d_in[1];
  const void* bq  = d_in[2];
  const void* Wk  = d_in[3];
  const void* bk  = d_in[4];
  const void* Wv  = d_in[5];
  const void* bv  = d_in[6];
  const void* Win = d_in[7];
  const void* bin = d_in[8];
  const void* W1  = d_in[9];
  const void* b1  = d_in[10];
  const void* W2  = d_in[11];
  const void* b2  = d_in[12];

  size_t off = 0;
  char* wsb = (char*)d_ws;
  auto alloc = [&](size_t bytes) {
    void* p = (void*)(wsb + off);
    off += (bytes + 255) & ~(size_t)255;
    return p;
  };
  int*   flag  = (int*)alloc(4);
  bf16*  xbf   = (bf16*)alloc((size_t)ROWS * D_MODEL * 2);
  bf16*  WqkvT = (bf16*)alloc((size_t)3200 * 1024 * 2);  // q|k|v|in rows + pad
  bf16*  W1T   = (bf16*)alloc((size_t)FF_HID * FF_IN * 2);
  bf16*  W2T   = (bf16*)alloc((size_t)D_MODEL * FF_HID * 2);
  float* biasf = (float*)alloc(6208 * 4);   // qkv | bin | b1 | b2
  bf16*  qkv   = (bf16*)alloc((size_t)ROWS * QKV_LD * 2);
  bf16*  vtb   = (bf16*)alloc((size_t)ROWS * D_MODEL * 2);
  bf16*  cbuf  = (bf16*)alloc((size_t)ROWS * FF_IN * 2);
  bf16*  hbuf  = (bf16*)alloc((size_t)ROWS * FF_HID * 2);
  float* b1f   = biasf + 3136;
  float* b2f   = biasf + 5184;

  const dim3 blk(256);
  const dim3 blk512(512);
  detect_kernel<<<1, blk, 0, stream>>>((const unsigned*)x, flag);

  x_to_bf16_kernel<<<(ROWS * D_MODEL) / 2048, blk, 0, stream>>>(x, xbf, flag);
  bias_all_kernel<<<25, blk, 0, stream>>>(bq, bk, bv, bin, b1, b2, biasf, flag);

  TransJobs J;
  J.src[0] = Wq;  J.dst[0] = WqkvT;                        J.R[0] = 1024; J.C[0] = 1024; J.scale[0] = 0.125f * LOG2E;
  J.src[1] = Wk;  J.dst[1] = WqkvT + (size_t)1024 * 1024;  J.R[1] = 1024; J.C[1] = 1024; J.scale[1] = 1.0f;
  J.src[2] = Wv;  J.dst[2] = WqkvT + (size_t)2048 * 1024;  J.R[2] = 1024; J.C[2] = 1024; J.scale[2] = 1.0f;
  J.src[3] = Win; J.dst[3] = WqkvT + (size_t)3072 * 1024;  J.R[3] = 1024; J.C[3] = 64;   J.scale[3] = 1.0f;
  J.src[4] = W1;  J.dst[4] = W1T;                          J.R[4] = 1088; J.C[4] = 2048; J.scale[4] = 1.0f;
  J.src[5] = W2;  J.dst[5] = W2T;                          J.R[5] = 2048; J.C[5] = 1024; J.scale[5] = 1.0f;
  int base = 0;
  for (int j = 0; j < 6; j++) {
    J.tiles_x[j] = J.C[j] / 32;
    J.tile_base[j] = base;
    base += (J.R[j] / 32) * (J.C[j] / 32);
  }
  J.tile_base[6] = base;
  transpose_all_kernel<<<base, blk, 0, stream>>>(J, flag);

  // fused QKV + in-proj projection: N=3136 (padded grid to 3200);
  // cols [0,3072) -> qkv (ldc 3072), [3072,3136) -> cbuf tail (ldc 1088)
  gemm_bt<128, false, false><<<dim3(ROWS / 256, 25), blk512, 0, stream>>>(
      xbf, WqkvT, biasf, qkv, 3200, 1024, QKV_LD,
      cbuf + 1024, FF_IN, 3072, 3136, nullptr);

  transpose_v_kernel<<<dim3(SEQ / 32, HDIM / 32, BSZ * N_HEADS), blk, 0, stream>>>(qkv, vtb);

  attn_kernel<<<dim3(1024), blk, 0, stream>>>(qkv, vtb, cbuf);

  // FFN
  gemm_bt<128, true, false><<<dim3(ROWS / 256, FF_HID / 128), blk512, 0, stream>>>(
      cbuf, W1T, b1f, hbuf, FF_HID, FF_IN, FF_HID,
      nullptr, 0, FF_HID, FF_HID, nullptr);
  gemm_bt<128, false, true><<<dim3(ROWS / 256, D_MODEL / 128), blk512, 0, stream>>>(
      hbuf, W2T, b2f, d_out, D_MODEL, FF_HID, D_MODEL,
      nullptr, 0, D_MODEL, D_MODEL, flag);
}

// Round 3
// 380.996 us; speedup vs baseline: 1.0938x; 1.0938x over previous
//
#include <hip/hip_runtime.h>

typedef __bf16 bf16;
typedef __attribute__((ext_vector_type(8))) __bf16 bf16x8;
typedef __attribute__((ext_vector_type(4))) __bf16 bf16x4;
typedef __attribute__((ext_vector_type(4))) short short4_t;
typedef __attribute__((ext_vector_type(4))) float floatx4;

typedef const void __attribute__((address_space(1)))* gas1p;
typedef void __attribute__((address_space(3)))* las3p;

#define LOG2E 1.44269504088896340736f

static constexpr int D_MODEL = 1024;
static constexpr int N_HEADS = 16;
static constexpr int HDIM    = 64;
static constexpr int BSZ     = 8;
static constexpr int SEQ     = 1024;
static constexpr int ROWS    = BSZ * SEQ;   // 8192
static constexpr int FF_IN   = 1088;        // 17*64
static constexpr int FF_HID  = 2048;
static constexpr int QKV_LD  = 3072;        // q|k|v row stride in qkv buffer

__device__ __forceinline__ floatx4 mfma_bf16(bf16x8 a, bf16x8 b, floatx4 c) {
  return __builtin_amdgcn_mfma_f32_16x16x32_bf16(a, b, c, 0, 0, 0);
}

__device__ __forceinline__ floatx4 mfma16(bf16x4 a, bf16x4 b, floatx4 c) {
#if __has_builtin(__builtin_amdgcn_mfma_f32_16x16x16_bf16)
  return __builtin_amdgcn_mfma_f32_16x16x16_bf16(a, b, c, 0, 0, 0);
#else
  return __builtin_amdgcn_mfma_f32_16x16x16bf16_1k(
      __builtin_bit_cast(short4_t, a), __builtin_bit_cast(short4_t, b), c, 0, 0, 0);
#endif
}

__device__ __forceinline__ float flex_load(const void* src, size_t idx, int isbf) {
  return isbf ? (float)((const bf16*)src)[idx] : ((const float*)src)[idx];
}

// ---------------- dtype detection (fp32 vs bf16 storage) ----------------
__global__ void detect_kernel(const unsigned* __restrict__ w, int* __restrict__ flag) {
  __shared__ int cnt;
  if (threadIdx.x == 0) cnt = 0;
  __syncthreads();
  int hits = 0;
  for (int i = threadIdx.x; i < 4096; i += 256) {
    const unsigned v = w[(size_t)i * 997 + 13];
    const unsigned b = (v >> 8) & 0x7F;
    hits += (b >= 0x3B && b <= 0x41) ? 1 : 0;
  }
  atomicAdd(&cnt, hits);
  __syncthreads();
  if (threadIdx.x == 0) *flag = (cnt > 2048) ? 1 : 0;
}

// ---------------- x -> bf16, 8 elems/thread ----------------
__global__ __launch_bounds__(256)
void x_to_bf16_kernel(const void* __restrict__ src, bf16* __restrict__ dst,
                      const int* __restrict__ flag) {
  const int isbf = *flag;
  const size_t i = ((size_t)blockIdx.x * 256 + threadIdx.x) * 8;
  bf16x8 o;
  if (isbf) {
    o = *reinterpret_cast<const bf16x8*>((const bf16*)src + i);
  } else {
    const float4 f0 = *reinterpret_cast<const float4*>((const float*)src + i);
    const float4 f1 = *reinterpret_cast<const float4*>((const float*)src + i + 4);
    o[0] = (bf16)f0.x; o[1] = (bf16)f0.y; o[2] = (bf16)f0.z; o[3] = (bf16)f0.w;
    o[4] = (bf16)f1.x; o[5] = (bf16)f1.y; o[6] = (bf16)f1.z; o[7] = (bf16)f1.w;
  }
  *reinterpret_cast<bf16x8*>(dst + i) = o;
}

// ---------------- all 6 biases -> one fp32 buffer (q scaled 1/8 * log2e) ----------------
__global__ __launch_bounds__(256)
void bias_all_kernel(const void* bq, const void* bk, const void* bv,
                     const void* bin, const void* b1, const void* b2,
                     float* __restrict__ dst, const int* __restrict__ flag) {
  const int isbf = *flag;
  const int i = blockIdx.x * 256 + threadIdx.x;
  if (i < 1024)      dst[i] = flex_load(bq, i, isbf) * (0.125f * LOG2E);
  else if (i < 2048) dst[i] = flex_load(bk, i - 1024, isbf);
  else if (i < 3072) dst[i] = flex_load(bv, i - 2048, isbf);
  else if (i < 3136) dst[i] = flex_load(bin, i - 3072, isbf);
  else if (i < 5184) dst[i] = flex_load(b1, i - 3136, isbf);
  else if (i < 6208) dst[i] = flex_load(b2, i - 5184, isbf);
}

// ---------------- all weight transposes in one launch ----------------
struct TransJobs {
  const void* src[6];
  bf16* dst[6];
  int R[6], C[6];
  int tiles_x[6];
  int tile_base[7];
  float scale[6];
};

__global__ __launch_bounds__(256)
void transpose_all_kernel(TransJobs J, const int* __restrict__ flag) {
  __shared__ float tile[32][33];
  const int isbf = *flag;
  const int bid = blockIdx.x;
  int j = 0;
#pragma unroll
  for (int t = 1; t < 6; t++) j += (bid >= J.tile_base[t]) ? 1 : 0;
  const int t = bid - J.tile_base[j];
  const int c0 = (t % J.tiles_x[j]) * 32, r0 = (t / J.tiles_x[j]) * 32;
  const void* src = J.src[j];
  bf16* dst = J.dst[j];
  const int R = J.R[j], C = J.C[j];
  const float scale = J.scale[j];
  const int tx = threadIdx.x & 31, ty = threadIdx.x >> 5;
  for (int i = ty; i < 32; i += 8)
    tile[i][tx] = flex_load(src, (size_t)(r0 + i) * C + (c0 + tx), isbf);
  __syncthreads();
  for (int i = ty; i < 32; i += 8)
    dst[(size_t)(c0 + i) * R + (r0 + tx)] = (bf16)(tile[tx][i] * scale);
}

// ---------------- GEMM: C[M,N] = A[M,K] @ BT[N,K]^T + bias ----------------
// Round-0 structure restored (128x128, BK=64, 256 thr, 2-barrier, 32 KB LDS,
// 5 blocks/CU co-residency — r2's deep pipeline at 1 block/CU measured
// MfmaUtil 20.7% / 104 us, reproducing m196's coarse-phase-split regression).
// NEW (round 3): V_TRANS epilogue — for QKV blocks whose 128 output cols fall
// in the V range [2048,3072), each wave transposes its own 64x64 V tile
// through a private 8 KB LDS slab (reusing As/Bs space after the last
// barrier; XOR-swizzled) and stores coalesced bf16x8 rows directly into
// vt[b,h,d,i]. Removes the separate transpose_v kernel (32 MB traffic +
// launch) and 16 MB of qkv writes.
template <int BN, bool DO_RELU, bool OUT_FLEX, bool V_TRANS>
__global__ __launch_bounds__(256)
void gemm_bt(const bf16* __restrict__ A, const bf16* __restrict__ BT,
             const float* __restrict__ bias,
             void* __restrict__ Cv, int N, int K, int ldc,
             bf16* __restrict__ C2, int ldc2, int nsplit, int nvalid,
             bf16* __restrict__ vt_out, const int* __restrict__ flag) {
  constexpr int BM = 128, BK = 64;
  constexpr int TCN = BN / 32;
  constexpr int ACH = (BM * BK) / (256 * 8);   // 4
  constexpr int BCH = (BN * BK) / (256 * 8);   // 4 (BN=128)
  __shared__ __align__(16) char smem_raw[(BM * BK + BN * BK) * 2];  // 32 KB
  bf16* As = (bf16*)smem_raw;
  bf16* Bs = As + BM * BK;
  const int tid = threadIdx.x;
  const int wave = tid >> 6, lane = tid & 63;
  const int quad = lane >> 4, lo = lane & 15;
  const int wm = wave >> 1, wn = wave & 1;
  const int m0 = blockIdx.x * BM;
  const int n0 = blockIdx.y * BN;

  floatx4 acc[4][TCN];
#pragma unroll
  for (int i = 0; i < 4; i++)
#pragma unroll
    for (int j = 0; j < TCN; j++) acc[i][j] = floatx4{0.f, 0.f, 0.f, 0.f};

  for (int kb = 0; kb < K; kb += BK) {
#pragma unroll
    for (int u = 0; u < ACH; u++) {
      const int c = u * 256 + tid;
      const int row = c >> 3, col = c & 7;
      const int gcol = col ^ (row & 7);
      const bf16* g = A + (size_t)(m0 + row) * K + kb + gcol * 8;
      __builtin_amdgcn_global_load_lds((gas1p)g, (las3p)(As + c * 8), 16, 0, 0);
    }
#pragma unroll
    for (int u = 0; u < BCH; u++) {
      const int c = u * 256 + tid;
      const int row = c >> 3, col = c & 7;
      const int gcol = col ^ (row & 7);
      const bf16* g = BT + (size_t)(n0 + row) * K + kb + gcol * 8;
      __builtin_amdgcn_global_load_lds((gas1p)g, (las3p)(Bs + c * 8), 16, 0, 0);
    }
    __syncthreads();
#pragma unroll
    for (int kk = 0; kk < 2; kk++) {
      bf16x8 af[4], bfr[TCN];
#pragma unroll
      for (int tr = 0; tr < 4; tr++) {
        const int row = wm * 64 + tr * 16 + lo;
        const int cc = (kk * 4 + quad) ^ (lo & 7);
        af[tr] = *reinterpret_cast<const bf16x8*>(As + row * BK + cc * 8);
      }
#pragma unroll
      for (int tc = 0; tc < TCN; tc++) {
        const int row = wn * (BN / 2) + tc * 16 + lo;
        const int cc = (kk * 4 + quad) ^ (lo & 7);
        bfr[tc] = *reinterpret_cast<const bf16x8*>(Bs + row * BK + cc * 8);
      }
#pragma unroll
      for (int tr = 0; tr < 4; tr++)
#pragma unroll
        for (int tc = 0; tc < TCN; tc++)
          acc[tr][tc] = mfma_bf16(af[tr], bfr[tc], acc[tr][tc]);
    }
    __syncthreads();
  }

  // ---- V-transpose epilogue (block-uniform branch) ----
  if (V_TRANS && n0 >= 2048 && n0 < 3072) {
    // wave covers cols n0 + wn*64 + (tc*16+lo) -> one head: h, d = tc*16+lo
    const int h = ((n0 - 2048) >> 6) + wn;
    const int b = m0 >> 10;                       // 128 | 1024 so uniform
    const int ibase = (m0 & 1023) + wm * 64;      // wave's 64 i-rows
    bf16* L = ((bf16*)smem_raw) + wave * 4096;    // private 64x64 slab (8 KB)
#pragma unroll
    for (int tc = 0; tc < TCN; tc++) {
      const int d = tc * 16 + lo;
      const float bval = bias[n0 + wn * 64 + d];
#pragma unroll
      for (int tr = 0; tr < 4; tr++) {
        const int iin = tr * 16 + quad * 4;       // 4-aligned, 0..60
        bf16x4 p;
#pragma unroll
        for (int r = 0; r < 4; r++) p[r] = (bf16)(acc[tr][tc][r] + bval);
        *reinterpret_cast<bf16x4*>(L + d * 64 + (iin ^ ((d & 7) << 3))) = p;
      }
    }
    asm volatile("s_waitcnt lgkmcnt(0)" ::: "memory");  // wave-local WAR/RAW
    bf16* dst = vt_out + (size_t)(b * 16 + h) * (HDIM * SEQ) + ibase;
#pragma unroll
    for (int w8 = 0; w8 < 8; w8++) {
      const int dp = w8 * 8 + (lane >> 3);        // d-row
      const int ip = (lane & 7) * 8;              // 8-aligned i-chunk
      const bf16x8 v = *reinterpret_cast<const bf16x8*>(
          L + dp * 64 + (ip ^ ((dp & 7) << 3)));
      *reinterpret_cast<bf16x8*>(dst + (size_t)dp * SEQ + ip) = v;
    }
    return;
  }

  const int isbf = OUT_FLEX ? *flag : 1;
#pragma unroll
  for (int tc = 0; tc < TCN; tc++) {
    const int col = n0 + wn * (BN / 2) + tc * 16 + lo;
    const float bval = bias[col];
    if (col < nsplit) {
#pragma unroll
      for (int tr = 0; tr < 4; tr++) {
        const int rbase = m0 + wm * 64 + tr * 16 + quad * 4;
#pragma unroll
        for (int r = 0; r < 4; r++) {
          float v = acc[tr][tc][r] + bval;
          if (DO_RELU) v = fmaxf(v, 0.f);
          const size_t idx = (size_t)(rbase + r) * ldc + col;
          if (!OUT_FLEX || isbf) ((bf16*)Cv)[idx] = (bf16)v;
          else                   ((float*)Cv)[idx] = v;
        }
      }
    } else if (col < nvalid) {
#pragma unroll
      for (int tr = 0; tr < 4; tr++) {
        const int rbase = m0 + wm * 64 + tr * 16 + quad * 4;
#pragma unroll
        for (int r = 0; r < 4; r++) {
          float v = acc[tr][tc][r] + bval;
          if (DO_RELU) v = fmaxf(v, 0.f);
          C2[(size_t)(rbase + r) * ldc2 + (col - nsplit)] = (bf16)v;
        }
      }
    }
  }
}

// ---------------- flash attention: S^T formulation + LDS staging ----------------
// Single-buffer 16 KB structure (max co-residency); LOG2E folded into q scale
// (exp2f directly); setprio around MFMA clusters.
__global__ __launch_bounds__(256)
void attn_kernel(const bf16* __restrict__ QKV, const bf16* __restrict__ Vt,
                 bf16* __restrict__ Cc) {
  __shared__ bf16 Ks[64 * 64];
  __shared__ bf16 Vs[64 * 64];
  const int bid = blockIdx.x;
  const int xcd = bid & 7, g = bid >> 3;
  const int ib = g & 7, bh = (g >> 3) * 8 + xcd;
  const int b = bh >> 4, h = bh & 15;
  const int i0 = ib * 128;
  const int tid = threadIdx.x, wave = tid >> 6, lane = tid & 63;
  const int quad = lane >> 4, lo = lane & 15;
  const int iw = i0 + wave * 32;
  const bf16* qptr = QKV + (size_t)b * SEQ * QKV_LD + h * HDIM;
  const bf16* kptr = QKV + (size_t)b * SEQ * QKV_LD + 1024 + h * HDIM;
  const bf16* vptr = Vt + (size_t)bh * HDIM * SEQ;

  bf16x8 qf[2][2];
#pragma unroll
  for (int it = 0; it < 2; it++)
#pragma unroll
    for (int kf = 0; kf < 2; kf++)
      qf[it][kf] = *reinterpret_cast<const bf16x8*>(
          qptr + (size_t)(iw + it * 16 + lo) * QKV_LD + kf * 32 + quad * 8);

  floatx4 oacc[2][4];
  float lrow[2] = {0.f, 0.f};
#pragma unroll
  for (int it = 0; it < 2; it++)
#pragma unroll
    for (int dt = 0; dt < 4; dt++) oacc[it][dt] = floatx4{0.f, 0.f, 0.f, 0.f};

  for (int jb = 0; jb < SEQ / 64; jb++) {
    const int j0 = jb * 64;
#pragma unroll
    for (int u = 0; u < 2; u++) {
      const int c = u * 256 + tid;
      const int row = c >> 3, col = c & 7;
      const int gcol = col ^ (row & 7);
      __builtin_amdgcn_global_load_lds(
          (gas1p)(kptr + (size_t)(j0 + row) * QKV_LD + gcol * 8),
          (las3p)(Ks + c * 8), 16, 0, 0);
      __builtin_amdgcn_global_load_lds(
          (gas1p)(vptr + (size_t)row * SEQ + j0 + gcol * 8),
          (las3p)(Vs + c * 8), 16, 0, 0);
    }
    __syncthreads();

    floatx4 sacc[2][4];
#pragma unroll
    for (int it = 0; it < 2; it++)
#pragma unroll
      for (int mt = 0; mt < 4; mt++) sacc[it][mt] = floatx4{0.f, 0.f, 0.f, 0.f};
    __builtin_amdgcn_s_setprio(1);
#pragma unroll
    for (int mt = 0; mt < 4; mt++) {
      const int r = mt * 16 + lo;
      const int cc0 = quad ^ (lo & 7);
      const int cc1 = (4 + quad) ^ (lo & 7);
      const bf16x8 k0 = *reinterpret_cast<const bf16x8*>(Ks + r * 64 + cc0 * 8);
      const bf16x8 k1 = *reinterpret_cast<const bf16x8*>(Ks + r * 64 + cc1 * 8);
#pragma unroll
      for (int it = 0; it < 2; it++) {
        sacc[it][mt] = mfma_bf16(k0, qf[it][0], sacc[it][mt]);
        sacc[it][mt] = mfma_bf16(k1, qf[it][1], sacc[it][mt]);
      }
    }
    __builtin_amdgcn_s_setprio(0);

    if (j0 == (iw & ~63)) {
#pragma unroll
      for (int it = 0; it < 2; it++) {
        const int ig = iw + it * 16 + lo;
#pragma unroll
        for (int mt = 0; mt < 4; mt++)
#pragma unroll
          for (int r = 0; r < 4; r++)
            if (j0 + mt * 16 + quad * 4 + r == ig) sacc[it][mt][r] = -1e30f;
      }
    }

    bf16x4 pfrag[2][4];
#pragma unroll
    for (int it = 0; it < 2; it++) {
      float s0 = 0.f, s1 = 0.f;
#pragma unroll
      for (int mt = 0; mt < 4; mt++) {
        bf16x4 pk;
#pragma unroll
        for (int r = 0; r < 4; r++) {
          const float p = exp2f(sacc[it][mt][r]);  // LOG2E folded into q scale
          if (mt & 1) s1 += p; else s0 += p;
          pk[r] = (bf16)p;
        }
        pfrag[it][mt] = pk;
      }
      float s = s0 + s1;
      s += __shfl_xor(s, 16);
      s += __shfl_xor(s, 32);
      lrow[it] += s;
    }

    __builtin_amdgcn_s_setprio(1);
#pragma unroll
    for (int dt = 0; dt < 4; dt++) {
      const int r = dt * 16 + lo;
#pragma unroll
      for (int kt = 0; kt < 4; kt++) {
        const int gch = kt * 2 + (quad >> 1);
        const int cc = gch ^ (lo & 7);
        const bf16x4 vf = *reinterpret_cast<const bf16x4*>(
            Vs + r * 64 + cc * 8 + (quad & 1) * 4);
#pragma unroll
        for (int it = 0; it < 2; it++)
          oacc[it][dt] = mfma16(vf, pfrag[it][kt], oacc[it][dt]);
      }
    }
    __builtin_amdgcn_s_setprio(0);
    __syncthreads();
  }

#pragma unroll
  for (int it = 0; it < 2; it++) {
    const int ig = iw + it * 16 + lo;
    const float inv = 1.0f / lrow[it];
    bf16* cb = Cc + ((size_t)b * SEQ + ig) * FF_IN + h * HDIM;
#pragma unroll
    for (int dt = 0; dt < 4; dt++) {
      bf16x4 o;
#pragma unroll
      for (int r = 0; r < 4; r++) o[r] = (bf16)(oacc[it][dt][r] * inv);
      *reinterpret_cast<bf16x4*>(cb + dt * 16 + quad * 4) = o;
    }
  }
}

// ---------------- launch ----------------
extern "C" void kernel_launch(void* const* d_in, const int* in_sizes, int n_in,
                              void* d_out, int out_size, void* d_ws, size_t ws_size,
                              hipStream_t stream) {
  (void)in_sizes; (void)n_in; (void)out_size; (void)ws_size;
  const void* x   = d_in[0];
  const void* Wq  = d_in[1];
  const void* bq  = d_in[2];
  const void* Wk  = d_in[3];
  const void* bk  = d_in[4];
  const void* Wv  = d_in[5];
  const void* bv  = d_in[6];
  const void* Win = d_in[7];
  const void* bin = d_in[8];
  const void* W1  = d_in[9];
  const void* b1  = d_in[10];
  const void* W2  = d_in[11];
  const void* b2  = d_in[12];

  size_t off = 0;
  char* wsb = (char*)d_ws;
  auto alloc = [&](size_t bytes) {
    void* p = (void*)(wsb + off);
    off += (bytes + 255) & ~(size_t)255;
    return p;
  };
  int*   flag  = (int*)alloc(4);
  bf16*  xbf   = (bf16*)alloc((size_t)ROWS * D_MODEL * 2);
  bf16*  WqkvT = (bf16*)alloc((size_t)3200 * 1024 * 2);  // q|k|v|in rows + pad
  bf16*  W1T   = (bf16*)alloc((size_t)FF_HID * FF_IN * 2);
  bf16*  W2T   = (bf16*)alloc((size_t)D_MODEL * FF_HID * 2);
  float* biasf = (float*)alloc(6208 * 4);   // qkv | bin | b1 | b2
  bf16*  qkv   = (bf16*)alloc((size_t)ROWS * QKV_LD * 2);
  bf16*  vtb   = (bf16*)alloc((size_t)ROWS * D_MODEL * 2);
  bf16*  cbuf  = (bf16*)alloc((size_t)ROWS * FF_IN * 2);
  bf16*  hbuf  = (bf16*)alloc((size_t)ROWS * FF_HID * 2);
  float* b1f   = biasf + 3136;
  float* b2f   = biasf + 5184;

  const dim3 blk(256);
  detect_kernel<<<1, blk, 0, stream>>>((const unsigned*)x, flag);

  x_to_bf16_kernel<<<(ROWS * D_MODEL) / 2048, blk, 0, stream>>>(x, xbf, flag);
  bias_all_kernel<<<25, blk, 0, stream>>>(bq, bk, bv, bin, b1, b2, biasf, flag);

  TransJobs J;
  J.src[0] = Wq;  J.dst[0] = WqkvT;                        J.R[0] = 1024; J.C[0] = 1024; J.scale[0] = 0.125f * LOG2E;
  J.src[1] = Wk;  J.dst[1] = WqkvT + (size_t)1024 * 1024;  J.R[1] = 1024; J.C[1] = 1024; J.scale[1] = 1.0f;
  J.src[2] = Wv;  J.dst[2] = WqkvT + (size_t)2048 * 1024;  J.R[2] = 1024; J.C[2] = 1024; J.scale[2] = 1.0f;
  J.src[3] = Win; J.dst[3] = WqkvT + (size_t)3072 * 1024;  J.R[3] = 1024; J.C[3] = 64;   J.scale[3] = 1.0f;
  J.src[4] = W1;  J.dst[4] = W1T;                          J.R[4] = 1088; J.C[4] = 2048; J.scale[4] = 1.0f;
  J.src[5] = W2;  J.dst[5] = W2T;                          J.R[5] = 2048; J.C[5] = 1024; J.scale[5] = 1.0f;
  int base = 0;
  for (int j = 0; j < 6; j++) {
    J.tiles_x[j] = J.C[j] / 32;
    J.tile_base[j] = base;
    base += (J.R[j] / 32) * (J.C[j] / 32);
  }
  J.tile_base[6] = base;
  transpose_all_kernel<<<base, blk, 0, stream>>>(J, flag);

  // fused QKV + in-proj projection: N=3136 (padded grid to 3200);
  // cols [0,2048) -> qkv (q|k), [2048,3072) -> vtb TRANSPOSED (V_TRANS
  // epilogue), [3072,3136) -> cbuf tail (ldc 1088), rest dropped.
  gemm_bt<128, false, false, true><<<dim3(ROWS / 128, 25), blk, 0, stream>>>(
      xbf, WqkvT, biasf, qkv, 3200, 1024, QKV_LD,
      cbuf + 1024, FF_IN, 3072, 3136, vtb, nullptr);

  attn_kernel<<<dim3(1024), blk, 0, stream>>>(qkv, vtb, cbuf);

  // FFN
  gemm_bt<128, true, false, false><<<dim3(ROWS / 128, FF_HID / 128), blk, 0, stream>>>(
      cbuf, W1T, b1f, hbuf, FF_HID, FF_IN, FF_HID,
      nullptr, 0, FF_HID, FF_HID, nullptr, nullptr);
  gemm_bt<128, false, true, false><<<dim3(ROWS / 128, D_MODEL / 128), blk, 0, stream>>>(
      hbuf, W2T, b2f, d_out, D_MODEL, FF_HID, D_MODEL,
      nullptr, 0, D_MODEL, D_MODEL, nullptr, flag);
}

// Round 4
// 372.610 us; speedup vs baseline: 1.1184x; 1.0225x over previous
//
#include <hip/hip_runtime.h>

typedef __bf16 bf16;
typedef __attribute__((ext_vector_type(8))) __bf16 bf16x8;
typedef __attribute__((ext_vector_type(4))) __bf16 bf16x4;
typedef __attribute__((ext_vector_type(4))) short short4_t;
typedef __attribute__((ext_vector_type(4))) float floatx4;

typedef const void __attribute__((address_space(1)))* gas1p;
typedef void __attribute__((address_space(3)))* las3p;

#define LOG2E 1.44269504088896340736f

static constexpr int D_MODEL = 1024;
static constexpr int N_HEADS = 16;
static constexpr int HDIM    = 64;
static constexpr int BSZ     = 8;
static constexpr int SEQ     = 1024;
static constexpr int ROWS    = BSZ * SEQ;   // 8192
static constexpr int FF_IN   = 1088;        // 17*64
static constexpr int FF_HID  = 2048;
static constexpr int QKV_LD  = 3072;        // q|k|v row stride in qkv buffer

__device__ __forceinline__ floatx4 mfma_bf16(bf16x8 a, bf16x8 b, floatx4 c) {
  return __builtin_amdgcn_mfma_f32_16x16x32_bf16(a, b, c, 0, 0, 0);
}

__device__ __forceinline__ floatx4 mfma16(bf16x4 a, bf16x4 b, floatx4 c) {
#if __has_builtin(__builtin_amdgcn_mfma_f32_16x16x16_bf16)
  return __builtin_amdgcn_mfma_f32_16x16x16_bf16(a, b, c, 0, 0, 0);
#else
  return __builtin_amdgcn_mfma_f32_16x16x16bf16_1k(
      __builtin_bit_cast(short4_t, a), __builtin_bit_cast(short4_t, b), c, 0, 0, 0);
#endif
}

__device__ __forceinline__ float fast_exp2(float x) {
#if __has_builtin(__builtin_amdgcn_exp2f)
  return __builtin_amdgcn_exp2f(x);   // raw v_exp_f32, no libm guards
#else
  return exp2f(x);
#endif
}

__device__ __forceinline__ float flex_load(const void* src, size_t idx, int isbf) {
  return isbf ? (float)((const bf16*)src)[idx] : ((const float*)src)[idx];
}

// ---------------- dtype detection (fp32 vs bf16 storage) ----------------
__global__ void detect_kernel(const unsigned* __restrict__ w, int* __restrict__ flag) {
  __shared__ int cnt;
  if (threadIdx.x == 0) cnt = 0;
  __syncthreads();
  int hits = 0;
  for (int i = threadIdx.x; i < 4096; i += 256) {
    const unsigned v = w[(size_t)i * 997 + 13];
    const unsigned b = (v >> 8) & 0x7F;
    hits += (b >= 0x3B && b <= 0x41) ? 1 : 0;
  }
  atomicAdd(&cnt, hits);
  __syncthreads();
  if (threadIdx.x == 0) *flag = (cnt > 2048) ? 1 : 0;
}

// ---------------- x -> bf16, 8 elems/thread ----------------
__global__ __launch_bounds__(256)
void x_to_bf16_kernel(const void* __restrict__ src, bf16* __restrict__ dst,
                      const int* __restrict__ flag) {
  const int isbf = *flag;
  const size_t i = ((size_t)blockIdx.x * 256 + threadIdx.x) * 8;
  bf16x8 o;
  if (isbf) {
    o = *reinterpret_cast<const bf16x8*>((const bf16*)src + i);
  } else {
    const float4 f0 = *reinterpret_cast<const float4*>((const float*)src + i);
    const float4 f1 = *reinterpret_cast<const float4*>((const float*)src + i + 4);
    o[0] = (bf16)f0.x; o[1] = (bf16)f0.y; o[2] = (bf16)f0.z; o[3] = (bf16)f0.w;
    o[4] = (bf16)f1.x; o[5] = (bf16)f1.y; o[6] = (bf16)f1.z; o[7] = (bf16)f1.w;
  }
  *reinterpret_cast<bf16x8*>(dst + i) = o;
}

// ---------------- all 6 biases -> one fp32 buffer (q scaled 1/8 * log2e) ----------------
__global__ __launch_bounds__(256)
void bias_all_kernel(const void* bq, const void* bk, const void* bv,
                     const void* bin, const void* b1, const void* b2,
                     float* __restrict__ dst, const int* __restrict__ flag) {
  const int isbf = *flag;
  const int i = blockIdx.x * 256 + threadIdx.x;
  if (i < 1024)      dst[i] = flex_load(bq, i, isbf) * (0.125f * LOG2E);
  else if (i < 2048) dst[i] = flex_load(bk, i - 1024, isbf);
  else if (i < 3072) dst[i] = flex_load(bv, i - 2048, isbf);
  else if (i < 3136) dst[i] = flex_load(bin, i - 3072, isbf);
  else if (i < 5184) dst[i] = flex_load(b1, i - 3136, isbf);
  else if (i < 6208) dst[i] = flex_load(b2, i - 5184, isbf);
}

// ---------------- all weight transposes in one launch ----------------
struct TransJobs {
  const void* src[6];
  bf16* dst[6];
  int R[6], C[6];
  int tiles_x[6];
  int tile_base[7];
  float scale[6];
};

__global__ __launch_bounds__(256)
void transpose_all_kernel(TransJobs J, const int* __restrict__ flag) {
  __shared__ float tile[32][33];
  const int isbf = *flag;
  const int bid = blockIdx.x;
  int j = 0;
#pragma unroll
  for (int t = 1; t < 6; t++) j += (bid >= J.tile_base[t]) ? 1 : 0;
  const int t = bid - J.tile_base[j];
  const int c0 = (t % J.tiles_x[j]) * 32, r0 = (t / J.tiles_x[j]) * 32;
  const void* src = J.src[j];
  bf16* dst = J.dst[j];
  const int R = J.R[j], C = J.C[j];
  const float scale = J.scale[j];
  const int tx = threadIdx.x & 31, ty = threadIdx.x >> 5;
  for (int i = ty; i < 32; i += 8)
    tile[i][tx] = flex_load(src, (size_t)(r0 + i) * C + (c0 + tx), isbf);
  __syncthreads();
  for (int i = ty; i < 32; i += 8)
    dst[(size_t)(c0 + i) * R + (r0 + tx)] = (bf16)(tile[tx][i] * scale);
}

// ---------------- GEMM: C[M,N] = A[M,K] @ BT[N,K]^T + bias ----------------
// m97-class structure (128x128, BK=64, 256 thr, 2-barrier, 32 KB LDS, ~5
// blocks/CU co-residency). V_TRANS epilogue: QKV blocks whose 128 output cols
// fall in [2048,3072) transpose their V tiles through wave-private LDS slabs
// straight into vt[b,h,d,i] (verified round 3: removed transpose_v, -17 us).
template <int BN, bool DO_RELU, bool OUT_FLEX, bool V_TRANS>
__global__ __launch_bounds__(256)
void gemm_bt(const bf16* __restrict__ A, const bf16* __restrict__ BT,
             const float* __restrict__ bias,
             void* __restrict__ Cv, int N, int K, int ldc,
             bf16* __restrict__ C2, int ldc2, int nsplit, int nvalid,
             bf16* __restrict__ vt_out, const int* __restrict__ flag) {
  constexpr int BM = 128, BK = 64;
  constexpr int TCN = BN / 32;
  constexpr int ACH = (BM * BK) / (256 * 8);   // 4
  constexpr int BCH = (BN * BK) / (256 * 8);   // 4 (BN=128)
  __shared__ __align__(16) char smem_raw[(BM * BK + BN * BK) * 2];  // 32 KB
  bf16* As = (bf16*)smem_raw;
  bf16* Bs = As + BM * BK;
  const int tid = threadIdx.x;
  const int wave = tid >> 6, lane = tid & 63;
  const int quad = lane >> 4, lo = lane & 15;
  const int wm = wave >> 1, wn = wave & 1;
  const int m0 = blockIdx.x * BM;
  const int n0 = blockIdx.y * BN;

  floatx4 acc[4][TCN];
#pragma unroll
  for (int i = 0; i < 4; i++)
#pragma unroll
    for (int j = 0; j < TCN; j++) acc[i][j] = floatx4{0.f, 0.f, 0.f, 0.f};

  for (int kb = 0; kb < K; kb += BK) {
#pragma unroll
    for (int u = 0; u < ACH; u++) {
      const int c = u * 256 + tid;
      const int row = c >> 3, col = c & 7;
      const int gcol = col ^ (row & 7);
      const bf16* g = A + (size_t)(m0 + row) * K + kb + gcol * 8;
      __builtin_amdgcn_global_load_lds((gas1p)g, (las3p)(As + c * 8), 16, 0, 0);
    }
#pragma unroll
    for (int u = 0; u < BCH; u++) {
      const int c = u * 256 + tid;
      const int row = c >> 3, col = c & 7;
      const int gcol = col ^ (row & 7);
      const bf16* g = BT + (size_t)(n0 + row) * K + kb + gcol * 8;
      __builtin_amdgcn_global_load_lds((gas1p)g, (las3p)(Bs + c * 8), 16, 0, 0);
    }
    __syncthreads();
#pragma unroll
    for (int kk = 0; kk < 2; kk++) {
      bf16x8 af[4], bfr[TCN];
#pragma unroll
      for (int tr = 0; tr < 4; tr++) {
        const int row = wm * 64 + tr * 16 + lo;
        const int cc = (kk * 4 + quad) ^ (lo & 7);
        af[tr] = *reinterpret_cast<const bf16x8*>(As + row * BK + cc * 8);
      }
#pragma unroll
      for (int tc = 0; tc < TCN; tc++) {
        const int row = wn * (BN / 2) + tc * 16 + lo;
        const int cc = (kk * 4 + quad) ^ (lo & 7);
        bfr[tc] = *reinterpret_cast<const bf16x8*>(Bs + row * BK + cc * 8);
      }
#pragma unroll
      for (int tr = 0; tr < 4; tr++)
#pragma unroll
        for (int tc = 0; tc < TCN; tc++)
          acc[tr][tc] = mfma_bf16(af[tr], bfr[tc], acc[tr][tc]);
    }
    __syncthreads();
  }

  // ---- V-transpose epilogue (block-uniform branch) ----
  if (V_TRANS && n0 >= 2048 && n0 < 3072) {
    const int h = ((n0 - 2048) >> 6) + wn;
    const int b = m0 >> 10;
    const int ibase = (m0 & 1023) + wm * 64;
    bf16* L = ((bf16*)smem_raw) + wave * 4096;    // private 64x64 slab (8 KB)
#pragma unroll
    for (int tc = 0; tc < TCN; tc++) {
      const int d = tc * 16 + lo;
      const float bval = bias[n0 + wn * 64 + d];
#pragma unroll
      for (int tr = 0; tr < 4; tr++) {
        const int iin = tr * 16 + quad * 4;
        bf16x4 p;
#pragma unroll
        for (int r = 0; r < 4; r++) p[r] = (bf16)(acc[tr][tc][r] + bval);
        *reinterpret_cast<bf16x4*>(L + d * 64 + (iin ^ ((d & 7) << 3))) = p;
      }
    }
    asm volatile("s_waitcnt lgkmcnt(0)" ::: "memory");
    bf16* dst = vt_out + (size_t)(b * 16 + h) * (HDIM * SEQ) + ibase;
#pragma unroll
    for (int w8 = 0; w8 < 8; w8++) {
      const int dp = w8 * 8 + (lane >> 3);
      const int ip = (lane & 7) * 8;
      const bf16x8 v = *reinterpret_cast<const bf16x8*>(
          L + dp * 64 + (ip ^ ((dp & 7) << 3)));
      *reinterpret_cast<bf16x8*>(dst + (size_t)dp * SEQ + ip) = v;
    }
    return;
  }

  const int isbf = OUT_FLEX ? *flag : 1;
#pragma unroll
  for (int tc = 0; tc < TCN; tc++) {
    const int col = n0 + wn * (BN / 2) + tc * 16 + lo;
    const float bval = bias[col];
    if (col < nsplit) {
#pragma unroll
      for (int tr = 0; tr < 4; tr++) {
        const int rbase = m0 + wm * 64 + tr * 16 + quad * 4;
#pragma unroll
        for (int r = 0; r < 4; r++) {
          float v = acc[tr][tc][r] + bval;
          if (DO_RELU) v = fmaxf(v, 0.f);
          const size_t idx = (size_t)(rbase + r) * ldc + col;
          if (!OUT_FLEX || isbf) ((bf16*)Cv)[idx] = (bf16)v;
          else                   ((float*)Cv)[idx] = v;
        }
      }
    } else if (col < nvalid) {
#pragma unroll
      for (int tr = 0; tr < 4; tr++) {
        const int rbase = m0 + wm * 64 + tr * 16 + quad * 4;
#pragma unroll
        for (int r = 0; r < 4; r++) {
          float v = acc[tr][tc][r] + bval;
          if (DO_RELU) v = fmaxf(v, 0.f);
          C2[(size_t)(rbase + r) * ldc2 + (col - nsplit)] = (bf16)v;
        }
      }
    }
  }
}

// ---------------- flash attention: S^T formulation + LDS staging ----------------
// Round-4: i-block 128 -> 64 rows (grid 1024 -> 2048, per-wave 16 rows, the
// `it` dimension deleted). Rationale: only 4 blocks/CU of work existed at
// grid 1024 (Occupancy 24%) while MfmaUtil+VALUBusy ~= 89%; doubling
// co-resident blocks gives cross-wave MFMA/VALU overlap (m114) and halves
// the tail. LDS stays 16 KB; VGPR drops with halved accumulator state.
// K/V staged 2x as often -> L2-served (well under L2 ceiling).
// fast_exp2 = raw v_exp_f32. 2-way bank conflict on PV b64 reads is the
// access-pattern floor and free per m136 (counter is a red herring).
__global__ __launch_bounds__(256)
void attn_kernel(const bf16* __restrict__ QKV, const bf16* __restrict__ Vt,
                 bf16* __restrict__ Cc) {
  __shared__ bf16 Ks[64 * 64];
  __shared__ bf16 Vs[64 * 64];
  const int bid = blockIdx.x;
  const int xcd = bid & 7, g = bid >> 3;
  const int ib = g & 15, bh = (g >> 4) * 8 + xcd;
  const int b = bh >> 4, h = bh & 15;
  const int i0 = ib * 64;
  const int tid = threadIdx.x, wave = tid >> 6, lane = tid & 63;
  const int quad = lane >> 4, lo = lane & 15;
  const int iw = i0 + wave * 16;
  const bf16* qptr = QKV + (size_t)b * SEQ * QKV_LD + h * HDIM;
  const bf16* kptr = QKV + (size_t)b * SEQ * QKV_LD + 1024 + h * HDIM;
  const bf16* vptr = Vt + (size_t)bh * HDIM * SEQ;

  bf16x8 qf[2];
#pragma unroll
  for (int kf = 0; kf < 2; kf++)
    qf[kf] = *reinterpret_cast<const bf16x8*>(
        qptr + (size_t)(iw + lo) * QKV_LD + kf * 32 + quad * 8);

  floatx4 oacc[4];
  float lrow = 0.f;
#pragma unroll
  for (int dt = 0; dt < 4; dt++) oacc[dt] = floatx4{0.f, 0.f, 0.f, 0.f};

  for (int jb = 0; jb < SEQ / 64; jb++) {
    const int j0 = jb * 64;
#pragma unroll
    for (int u = 0; u < 2; u++) {
      const int c = u * 256 + tid;
      const int row = c >> 3, col = c & 7;
      const int gcol = col ^ (row & 7);
      __builtin_amdgcn_global_load_lds(
          (gas1p)(kptr + (size_t)(j0 + row) * QKV_LD + gcol * 8),
          (las3p)(Ks + c * 8), 16, 0, 0);
      __builtin_amdgcn_global_load_lds(
          (gas1p)(vptr + (size_t)row * SEQ + j0 + gcol * 8),
          (las3p)(Vs + c * 8), 16, 0, 0);
    }
    __syncthreads();

    floatx4 sacc[4];
#pragma unroll
    for (int mt = 0; mt < 4; mt++) sacc[mt] = floatx4{0.f, 0.f, 0.f, 0.f};
    __builtin_amdgcn_s_setprio(1);
#pragma unroll
    for (int mt = 0; mt < 4; mt++) {
      const int r = mt * 16 + lo;
      const int cc0 = quad ^ (lo & 7);
      const int cc1 = (4 + quad) ^ (lo & 7);
      const bf16x8 k0 = *reinterpret_cast<const bf16x8*>(Ks + r * 64 + cc0 * 8);
      const bf16x8 k1 = *reinterpret_cast<const bf16x8*>(Ks + r * 64 + cc1 * 8);
      sacc[mt] = mfma_bf16(k0, qf[0], sacc[mt]);
      sacc[mt] = mfma_bf16(k1, qf[1], sacc[mt]);
    }
    __builtin_amdgcn_s_setprio(0);

    if (j0 == i0) {   // iw & ~63 == i0 for all waves (wave*16 < 64)
      const int ig = iw + lo;
#pragma unroll
      for (int mt = 0; mt < 4; mt++)
#pragma unroll
        for (int r = 0; r < 4; r++)
          if (j0 + mt * 16 + quad * 4 + r == ig) sacc[mt][r] = -1e30f;
    }

    bf16x4 pfrag[4];
    {
      float s0 = 0.f, s1 = 0.f;
#pragma unroll
      for (int mt = 0; mt < 4; mt++) {
        bf16x4 pk;
#pragma unroll
        for (int r = 0; r < 4; r++) {
          const float p = fast_exp2(sacc[mt][r]);  // LOG2E folded into q scale
          if (mt & 1) s1 += p; else s0 += p;
          pk[r] = (bf16)p;
        }
        pfrag[mt] = pk;
      }
      float s = s0 + s1;
      s += __shfl_xor(s, 16);
      s += __shfl_xor(s, 32);
      lrow += s;
    }

    __builtin_amdgcn_s_setprio(1);
#pragma unroll
    for (int dt = 0; dt < 4; dt++) {
      const int r = dt * 16 + lo;
#pragma unroll
      for (int kt = 0; kt < 4; kt++) {
        const int gch = kt * 2 + (quad >> 1);
        const int cc = gch ^ (lo & 7);
        const bf16x4 vf = *reinterpret_cast<const bf16x4*>(
            Vs + r * 64 + cc * 8 + (quad & 1) * 4);
        oacc[dt] = mfma16(vf, pfrag[kt], oacc[dt]);
      }
    }
    __builtin_amdgcn_s_setprio(0);
    __syncthreads();
  }

  {
    const int ig = iw + lo;
    const float inv = 1.0f / lrow;
    bf16* cb = Cc + ((size_t)b * SEQ + ig) * FF_IN + h * HDIM;
#pragma unroll
    for (int dt = 0; dt < 4; dt++) {
      bf16x4 o;
#pragma unroll
      for (int r = 0; r < 4; r++) o[r] = (bf16)(oacc[dt][r] * inv);
      *reinterpret_cast<bf16x4*>(cb + dt * 16 + quad * 4) = o;
    }
  }
}

// ---------------- launch ----------------
extern "C" void kernel_launch(void* const* d_in, const int* in_sizes, int n_in,
                              void* d_out, int out_size, void* d_ws, size_t ws_size,
                              hipStream_t stream) {
  (void)in_sizes; (void)n_in; (void)out_size; (void)ws_size;
  const void* x   = d_in[0];
  const void* Wq  = d_in[1];
  const void* bq  = d_in[2];
  const void* Wk  = d_in[3];
  const void* bk  = d_in[4];
  const void* Wv  = d_in[5];
  const void* bv  = d_in[6];
  const void* Win = d_in[7];
  const void* bin = d_in[8];
  const void* W1  = d_in[9];
  const void* b1  = d_in[10];
  const void* W2  = d_in[11];
  const void* b2  = d_in[12];

  size_t off = 0;
  char* wsb = (char*)d_ws;
  auto alloc = [&](size_t bytes) {
    void* p = (void*)(wsb + off);
    off += (bytes + 255) & ~(size_t)255;
    return p;
  };
  int*   flag  = (int*)alloc(4);
  bf16*  xbf   = (bf16*)alloc((size_t)ROWS * D_MODEL * 2);
  bf16*  WqkvT = (bf16*)alloc((size_t)3200 * 1024 * 2);  // q|k|v|in rows + pad
  bf16*  W1T   = (bf16*)alloc((size_t)FF_HID * FF_IN * 2);
  bf16*  W2T   = (bf16*)alloc((size_t)D_MODEL * FF_HID * 2);
  float* biasf = (float*)alloc(6208 * 4);   // qkv | bin | b1 | b2
  bf16*  qkv   = (bf16*)alloc((size_t)ROWS * QKV_LD * 2);
  bf16*  vtb   = (bf16*)alloc((size_t)ROWS * D_MODEL * 2);
  bf16*  cbuf  = (bf16*)alloc((size_t)ROWS * FF_IN * 2);
  bf16*  hbuf  = (bf16*)alloc((size_t)ROWS * FF_HID * 2);
  float* b1f   = biasf + 3136;
  float* b2f   = biasf + 5184;

  const dim3 blk(256);
  detect_kernel<<<1, blk, 0, stream>>>((const unsigned*)x, flag);

  x_to_bf16_kernel<<<(ROWS * D_MODEL) / 2048, blk, 0, stream>>>(x, xbf, flag);
  bias_all_kernel<<<25, blk, 0, stream>>>(bq, bk, bv, bin, b1, b2, biasf, flag);

  TransJobs J;
  J.src[0] = Wq;  J.dst[0] = WqkvT;                        J.R[0] = 1024; J.C[0] = 1024; J.scale[0] = 0.125f * LOG2E;
  J.src[1] = Wk;  J.dst[1] = WqkvT + (size_t)1024 * 1024;  J.R[1] = 1024; J.C[1] = 1024; J.scale[1] = 1.0f;
  J.src[2] = Wv;  J.dst[2] = WqkvT + (size_t)2048 * 1024;  J.R[2] = 1024; J.C[2] = 1024; J.scale[2] = 1.0f;
  J.src[3] = Win; J.dst[3] = WqkvT + (size_t)3072 * 1024;  J.R[3] = 1024; J.C[3] = 64;   J.scale[3] = 1.0f;
  J.src[4] = W1;  J.dst[4] = W1T;                          J.R[4] = 1088; J.C[4] = 2048; J.scale[4] = 1.0f;
  J.src[5] = W2;  J.dst[5] = W2T;                          J.R[5] = 2048; J.C[5] = 1024; J.scale[5] = 1.0f;
  int base = 0;
  for (int j = 0; j < 6; j++) {
    J.tiles_x[j] = J.C[j] / 32;
    J.tile_base[j] = base;
    base += (J.R[j] / 32) * (J.C[j] / 32);
  }
  J.tile_base[6] = base;
  transpose_all_kernel<<<base, blk, 0, stream>>>(J, flag);

  // fused QKV + in-proj projection: N=3136 (padded grid to 3200);
  // cols [0,2048) -> qkv (q|k), [2048,3072) -> vtb TRANSPOSED (V_TRANS
  // epilogue), [3072,3136) -> cbuf tail (ldc 1088), rest dropped.
  gemm_bt<128, false, false, true><<<dim3(ROWS / 128, 25), blk, 0, stream>>>(
      xbf, WqkvT, biasf, qkv, 3200, 1024, QKV_LD,
      cbuf + 1024, FF_IN, 3072, 3136, vtb, nullptr);

  attn_kernel<<<dim3(2048), blk, 0, stream>>>(qkv, vtb, cbuf);

  // FFN
  gemm_bt<128, true, false, false><<<dim3(ROWS / 128, FF_HID / 128), blk, 0, stream>>>(
      cbuf, W1T, b1f, hbuf, FF_HID, FF_IN, FF_HID,
      nullptr, 0, FF_HID, FF_HID, nullptr, nullptr);
  gemm_bt<128, false, true, false><<<dim3(ROWS / 128, D_MODEL / 128), blk, 0, stream>>>(
      hbuf, W2T, b2f, d_out, D_MODEL, FF_HID, D_MODEL,
      nullptr, 0, D_MODEL, D_MODEL, nullptr, flag);
}